// Round 9
// baseline (176.801 us; speedup 1.0000x reference)
//
#include <hip/hip_runtime.h>
#include <hip/hip_bf16.h>

#define BATCH 16384
#define EDIM  16
#define NOH   26
#define LL    50
#define KIN   461
#define KPAD  480
#define KLDS  488   // padded A-row stride in shorts: 976 B, 16B-aligned
#define ROWS  32    // rows per block

using bf16x8 = __attribute__((ext_vector_type(8))) short;
using f32x4  = __attribute__((ext_vector_type(4))) float;

static __device__ __forceinline__ unsigned short f2bf(float f) {
    union { float f; unsigned int u; } v; v.f = f;
    unsigned int r = v.u + 0x7FFFu + ((v.u >> 16) & 1u);   // round-to-nearest-even
    return (unsigned short)(r >> 16);
}
static __device__ __forceinline__ float bf2f(unsigned short u) {
    union { unsigned int u; float f; } v; v.u = ((unsigned int)u) << 16;
    return v.f;
}

// ---- pre-kernel: w0 (f32 [461,64]) -> bf16 MFMA B-fragment order in scratch ----
__global__ __launch_bounds__(256) void prep(const float* __restrict__ w0,
                                            unsigned short* __restrict__ w0f) {
    int idx = blockIdx.x * 256 + threadIdx.x;        // 30720 total
    if (idx < 30720) {
        int j    = idx & 7;
        int frag = idx >> 3;
        int lane = frag & 63;
        int tile = frag >> 6;
        int nt = tile / 15;
        int kt = tile - nt * 15;
        int k = kt * 32 + ((lane >> 4) << 3) + j;
        int n = (nt << 4) + (lane & 15);
        float v = (k < KIN) ? w0[k * 64 + n] : 0.f;
        w0f[idx] = f2bf(v);
    }
}

// ---- fused: gathers + FM -> LDS A-tile -> MFMA GEMM (B from global scratch) -> MLP -> sigmoid
// launch_bounds(512, 8): 8 waves/EU => 4 blocks/CU co-resident (LDS 4*39424 = 157.7 KB fits 160 KB)
__global__ __launch_bounds__(512, 8) void fused(
    const float* __restrict__ dense,      // [B,13]
    const int*   __restrict__ onehot,     // [B,26]
    const int*   __restrict__ mh_ids,     // [B,2,50]
    const float* __restrict__ mh_mask,    // [B,2,50]
    const float* __restrict__ fm_w,       // [V,1]
    const float* __restrict__ fm_emb,     // [V,16]
    const unsigned short* __restrict__ w0f, // [4*15*64*8] bf16 frag order
    const float* __restrict__ b0,         // [64]
    const float* __restrict__ w1,         // [64,12]
    const float* __restrict__ b1,         // [12]
    const float* __restrict__ concat_w,   // [29]
    const float* __restrict__ concat_b,   // [1]
    float* __restrict__ out)              // [B]
{
    __shared__ unsigned short As[ROWS * KLDS];   // 31,232 B  bf16 A-tile
    __shared__ unsigned short h0s[ROWS][68];     //  4,352 B  relu(h0) bf16, padded
    __shared__ float w1t[12 * 64];               //  3,072 B  transposed [j][k]
    __shared__ float part_s[ROWS];
    __shared__ float b0s[64];
    __shared__ float b1s[12];
    __shared__ float cwh[12];

    const int t  = threadIdx.x;
    const int wv = t >> 6;        // 0..7
    const int l  = t & 63;
    const int s  = l >> 2;        // slot lane (0..15)
    const int d  = l & 3;         // dim quarter
    const int row0 = blockIdx.x << 5;

    // stage W1^T, biases — thread-count-independent grid-stride (round-6 lesson)
    for (int i = t; i < 768; i += 512) { int k = i / 12, j = i - k * 12; w1t[j * 64 + k] = w1[i]; }
    if (t < 64)               b0s[t] = b0[t];
    if (t >= 64 && t < 76)    b1s[t - 64] = b1[t - 64];
    if (t >= 96 && t < 108)   cwh[t - 96] = concat_w[17 + (t - 96)];

    // ---- gather + FM for this wave's 4 rows ----
    for (int i = 0; i < 4; ++i) {
        const int r = (wv << 2) + i;      // local row 0..31
        const int b = row0 + r;

        const float v1 = (s < 10) ? 1.f : 0.f;
        int oid0 = onehot[b * NOH + s];
        int oid1 = (s < 10) ? onehot[b * NOH + 16 + s] : 0;

        int   mid[7]; float mmk[7];
        #pragma unroll
        for (int p = 0; p < 7; ++p) {
            int pi = p * 16 + s;
            bool valid = pi < 100;
            int f = (pi >= 50) ? 1 : 0;
            int ii = pi - f * 50;
            size_t off = ((size_t)b * 2 + f) * LL + ii;
            mid[p] = valid ? mh_ids[off]  : 0;
            mmk[p] = valid ? mh_mask[off] : 0.f;
        }

        // issue all gathers back-to-back
        float4 e0 = *(const float4*)(fm_emb + (size_t)oid0 * EDIM + d * 4);
        float4 e1 = *(const float4*)(fm_emb + (size_t)oid1 * EDIM + d * 4);
        float  wsa = fm_w[oid0];
        float  wsb = fm_w[oid1];
        float4 gm[7];
        #pragma unroll
        for (int p = 0; p < 7; ++p)
            gm[p] = *(const float4*)(fm_emb + (size_t)mid[p] * EDIM + d * 4);

        e1.x *= v1; e1.y *= v1; e1.z *= v1; e1.w *= v1;
        float wsum = (d == 0) ? (wsa + v1 * wsb) : 0.f;

        unsigned short* rowp = As + r * KLDS;
        {
            ushort4 u; u.x = f2bf(e0.x); u.y = f2bf(e0.y); u.z = f2bf(e0.z); u.w = f2bf(e0.w);
            *(ushort4*)(rowp + s * EDIM + d * 4) = u;
        }
        if (s < 10) {
            ushort4 u; u.x = f2bf(e1.x); u.y = f2bf(e1.y); u.z = f2bf(e1.z); u.w = f2bf(e1.w);
            *(ushort4*)(rowp + (16 + s) * EDIM + d * 4) = u;
        }

        float a0x=0,a0y=0,a0z=0,a0w=0, a1x=0,a1y=0,a1z=0,a1w=0, m0=0, m1=0;
        #pragma unroll
        for (int p = 0; p < 7; ++p) {
            int pi = p * 16 + s;
            float m = mmk[p];
            if (pi >= 50) { a1x += m*gm[p].x; a1y += m*gm[p].y; a1z += m*gm[p].z; a1w += m*gm[p].w; m1 += m; }
            else          { a0x += m*gm[p].x; a0y += m*gm[p].y; a0z += m*gm[p].z; a0w += m*gm[p].w; m0 += m; }
        }

        float ohx = e0.x + e1.x, ohy = e0.y + e1.y, ohz = e0.z + e1.z, ohw = e0.w + e1.w;
        float qx = e0.x*e0.x + e1.x*e1.x, qy = e0.y*e0.y + e1.y*e1.y;
        float qz = e0.z*e0.z + e1.z*e1.z, qw = e0.w*e0.w + e1.w*e1.w;

#define R4(v) { v += __shfl_xor(v, 4); v += __shfl_xor(v, 8); v += __shfl_xor(v, 16); v += __shfl_xor(v, 32); }
        R4(a0x) R4(a0y) R4(a0z) R4(a0w)
        R4(a1x) R4(a1y) R4(a1z) R4(a1w)
        R4(m0)  R4(m1)
        R4(ohx) R4(ohy) R4(ohz) R4(ohw)
        R4(qx)  R4(qy)  R4(qz)  R4(qw)
        R4(wsum)
#undef R4

        float inv0 = 1.f / fmaxf(m0, 1.f);
        float inv1 = 1.f / fmaxf(m1, 1.f);
        float h0x = a0x*inv0, h0y = a0y*inv0, h0z = a0z*inv0, h0w = a0w*inv0;
        float h1x = a1x*inv1, h1y = a1y*inv1, h1z = a1z*inv1, h1w = a1w*inv1;

        if (s == 0) {
            ushort4 u; u.x = f2bf(h0x); u.y = f2bf(h0y); u.z = f2bf(h0z); u.w = f2bf(h0w);
            *(ushort4*)(rowp + 26 * EDIM + d * 4) = u;
        }
        if (s == 1) {
            ushort4 u; u.x = f2bf(h1x); u.y = f2bf(h1y); u.z = f2bf(h1z); u.w = f2bf(h1w);
            *(ushort4*)(rowp + 27 * EDIM + d * 4) = u;
        }

        float sx = ohx + h0x + h1x, sy = ohy + h0y + h1y, sz = ohz + h0z + h1z, sw = ohw + h0w + h1w;
        float tx = qx + h0x*h0x + h1x*h1x, ty = qy + h0y*h0y + h1y*h1y;
        float tz = qz + h0z*h0z + h1z*h1z, tw = qw + h0w*h0w + h1w*h1w;
        float f2x = 0.5f * (sx*sx - tx), f2y = 0.5f * (sy*sy - ty);
        float f2z = 0.5f * (sz*sz - tz), f2w = 0.5f * (sw*sw - tw);

        float cw0 = concat_w[0];
        float c0 = concat_w[1 + d*4 + 0], c1 = concat_w[1 + d*4 + 1];
        float c2 = concat_w[1 + d*4 + 2], c3 = concat_w[1 + d*4 + 3];
        float part = f2x*c0 + f2y*c1 + f2z*c2 + f2w*c3 + wsum * cw0;
        part += __shfl_xor(part, 1);
        part += __shfl_xor(part, 2);
        if (l == 0) part_s[r] = part + concat_b[0];

        if (l < 32) {
            float v = (l < 13) ? dense[b * 13 + l] : 0.f;
            rowp[448 + l] = f2bf(v);
        }
    }
    __syncthreads();

    // ---- MFMA: 8 waves -> 2 row-tiles x 4 col-tiles ----
    const int rt = wv >> 2, nt = wv & 3;
    const int c = l & 15, g = l >> 4;

    f32x4 acc = {0.f, 0.f, 0.f, 0.f};
    const unsigned short* ap = As + (rt * 16 + c) * KLDS + (g << 3);
    const unsigned short* bgp = w0f + ((size_t)(nt * 15) * 64 + l) * 8;

    #pragma unroll
    for (int kt = 0; kt < 15; ++kt) {
        bf16x8 a = *(const bf16x8*)(ap + kt * 32);
        bf16x8 bb = *(const bf16x8*)(bgp + (size_t)kt * 64 * 8);
        acc = __builtin_amdgcn_mfma_f32_16x16x32_bf16(a, bb, acc, 0, 0, 0);
    }

    // C layout: col = lane&15, row = (lane>>4)*4 + reg
    #pragma unroll
    for (int reg = 0; reg < 4; ++reg)
        h0s[rt * 16 + g * 4 + reg][nt * 16 + c] = f2bf(fmaxf(acc[reg] + b0s[nt * 16 + c], 0.f));
    __syncthreads();

    // ---- layer 2 + concat + sigmoid: waves 0..1, each handles 16 rows ----
    if (wv < 2) {
        float s0 = b1s[g*3 + 0], s1 = b1s[g*3 + 1], s2 = b1s[g*3 + 2];
        const unsigned short* hrow = &h0s[wv * 16 + c][0];
        #pragma unroll
        for (int k8 = 0; k8 < 8; ++k8) {
            ushort4 ha = *(const ushort4*)(hrow + k8 * 8 + 0);
            ushort4 hb = *(const ushort4*)(hrow + k8 * 8 + 4);
            float h[8] = { bf2f(ha.x), bf2f(ha.y), bf2f(ha.z), bf2f(ha.w),
                           bf2f(hb.x), bf2f(hb.y), bf2f(hb.z), bf2f(hb.w) };
            #pragma unroll
            for (int j = 0; j < 8; ++j) {
                int k = k8 * 8 + j;
                s0 += h[j] * w1t[(g*3 + 0) * 64 + k];
                s1 += h[j] * w1t[(g*3 + 1) * 64 + k];
                s2 += h[j] * w1t[(g*3 + 2) * 64 + k];
            }
        }
        float hd = fmaxf(s0, 0.f)*cwh[g*3] + fmaxf(s1, 0.f)*cwh[g*3+1] + fmaxf(s2, 0.f)*cwh[g*3+2];
        hd += __shfl_xor(hd, 16);
        hd += __shfl_xor(hd, 32);
        if (g == 0) {
            int rr = row0 + wv * 16 + c;
            float x = part_s[wv * 16 + c] + hd;
            out[rr] = 1.f / (1.f + __expf(-x));
        }
    }
}

extern "C" void kernel_launch(void* const* d_in, const int* in_sizes, int n_in,
                              void* d_out, int out_size, void* d_ws, size_t ws_size,
                              hipStream_t stream) {
    const float* dense   = (const float*)d_in[0];
    const int*   onehot  = (const int*)  d_in[1];
    const int*   mh_ids  = (const int*)  d_in[2];
    const float* mh_mask = (const float*)d_in[3];
    const float* fm_w    = (const float*)d_in[4];
    const float* fm_emb  = (const float*)d_in[5];
    const float* w0      = (const float*)d_in[6];
    const float* b0      = (const float*)d_in[7];
    const float* w1      = (const float*)d_in[8];
    const float* b1      = (const float*)d_in[9];
    const float* cw      = (const float*)d_in[10];
    const float* cb      = (const float*)d_in[11];

    unsigned short* w0f = (unsigned short*)d_ws;   // 61,440 B

    hipLaunchKernelGGL(prep, dim3(120), dim3(256), 0, stream, w0, w0f);
    hipLaunchKernelGGL(fused, dim3(BATCH / ROWS), dim3(512), 0, stream,
                       dense, onehot, mh_ids, mh_mask, fm_w, fm_emb,
                       w0f, b0, w1, b1, cw, cb, (float*)d_out);
}

// Round 10
// 159.111 us; speedup vs baseline: 1.1112x; 1.1112x over previous
//
#include <hip/hip_runtime.h>
#include <hip/hip_bf16.h>

#define BATCH 16384
#define EDIM  16
#define NOH   26
#define LL    50
#define KIN   461
#define KPAD  480
#define KLDS  488   // padded A-row stride in shorts: 976 B, 16B-aligned
#define ROWS  32    // rows per block

using bf16x8 = __attribute__((ext_vector_type(8))) short;
using f32x4  = __attribute__((ext_vector_type(4))) float;

static __device__ __forceinline__ unsigned short f2bf(float f) {
    union { float f; unsigned int u; } v; v.f = f;
    unsigned int r = v.u + 0x7FFFu + ((v.u >> 16) & 1u);   // round-to-nearest-even
    return (unsigned short)(r >> 16);
}
static __device__ __forceinline__ float bf2f(unsigned short u) {
    union { unsigned int u; float f; } v; v.u = ((unsigned int)u) << 16;
    return v.f;
}

// ---- pre-kernel: w0 (f32 [461,64]) -> bf16 MFMA B-fragment order in scratch ----
__global__ __launch_bounds__(256) void prep(const float* __restrict__ w0,
                                            unsigned short* __restrict__ w0f) {
    int idx = blockIdx.x * 256 + threadIdx.x;        // 30720 total
    if (idx < 30720) {
        int j    = idx & 7;
        int frag = idx >> 3;
        int lane = frag & 63;
        int tile = frag >> 6;
        int nt = tile / 15;
        int kt = tile - nt * 15;
        int k = kt * 32 + ((lane >> 4) << 3) + j;
        int n = (nt << 4) + (lane & 15);
        float v = (k < KIN) ? w0[k * 64 + n] : 0.f;
        w0f[idx] = f2bf(v);
    }
}

// ---- fused, wave-specialized pipeline:
//  S1: all 8 waves gather rows 0-15       | barrier
//  S2: waves 0-3 GEMM half0  ||  waves 4-7 gather rows 16-31   | barrier
//  S3: waves 0-3 GEMM half1  ||  wave 4 tail half0             | barrier
//  S4: wave 0 tail half1
__global__ __launch_bounds__(512, 4) void fused(
    const float* __restrict__ dense,      // [B,13]
    const int*   __restrict__ onehot,     // [B,26]
    const int*   __restrict__ mh_ids,     // [B,2,50]
    const float* __restrict__ mh_mask,    // [B,2,50]
    const float* __restrict__ fm_w,       // [V,1]
    const float* __restrict__ fm_emb,     // [V,16]
    const unsigned short* __restrict__ w0f, // [4*15*64*8] bf16 frag order
    const float* __restrict__ b0,         // [64]
    const float* __restrict__ w1,         // [64,12]
    const float* __restrict__ b1,         // [12]
    const float* __restrict__ concat_w,   // [29]
    const float* __restrict__ concat_b,   // [1]
    float* __restrict__ out)              // [B]
{
    __shared__ unsigned short As[ROWS * KLDS];   // 31,232 B  bf16 A-tile
    __shared__ unsigned short h0s[ROWS][68];     //  4,352 B  relu(h0) bf16, padded
    __shared__ float w1t[12 * 64];               //  3,072 B  transposed [j][k]
    __shared__ float part_s[ROWS];
    __shared__ float b0s[64];
    __shared__ float b1s[12];
    __shared__ float cwh[12];

    const int t  = threadIdx.x;
    const int wv = t >> 6;        // 0..7
    const int l  = t & 63;
    const int s  = l >> 2;        // slot lane (0..15)
    const int d  = l & 3;         // dim quarter
    const int row0 = blockIdx.x << 5;

    // stage W1^T, biases — thread-count-independent grid-stride (round-6 lesson)
    for (int i = t; i < 768; i += 512) { int k = i / 12, j = i - k * 12; w1t[j * 64 + k] = w1[i]; }
    if (t < 64)               b0s[t] = b0[t];
    if (t >= 64 && t < 76)    b1s[t - 64] = b1[t - 64];
    if (t >= 96 && t < 108)   cwh[t - 96] = concat_w[17 + (t - 96)];

    auto gather_row = [&](int r) {
        const int b = row0 + r;
        const float v1 = (s < 10) ? 1.f : 0.f;
        int oid0 = onehot[b * NOH + s];
        int oid1 = (s < 10) ? onehot[b * NOH + 16 + s] : 0;

        int   mid[7]; float mmk[7];
        #pragma unroll
        for (int p = 0; p < 7; ++p) {
            int pi = p * 16 + s;
            bool valid = pi < 100;
            int f = (pi >= 50) ? 1 : 0;
            int ii = pi - f * 50;
            size_t off = ((size_t)b * 2 + f) * LL + ii;
            mid[p] = valid ? mh_ids[off]  : 0;
            mmk[p] = valid ? mh_mask[off] : 0.f;
        }

        // issue all gathers back-to-back
        float4 e0 = *(const float4*)(fm_emb + (size_t)oid0 * EDIM + d * 4);
        float4 e1 = *(const float4*)(fm_emb + (size_t)oid1 * EDIM + d * 4);
        float  wsa = fm_w[oid0];
        float  wsb = fm_w[oid1];
        float4 gm[7];
        #pragma unroll
        for (int p = 0; p < 7; ++p)
            gm[p] = *(const float4*)(fm_emb + (size_t)mid[p] * EDIM + d * 4);

        e1.x *= v1; e1.y *= v1; e1.z *= v1; e1.w *= v1;
        float wsum = (d == 0) ? (wsa + v1 * wsb) : 0.f;

        unsigned short* rowp = As + r * KLDS;
        {
            ushort4 u; u.x = f2bf(e0.x); u.y = f2bf(e0.y); u.z = f2bf(e0.z); u.w = f2bf(e0.w);
            *(ushort4*)(rowp + s * EDIM + d * 4) = u;
        }
        if (s < 10) {
            ushort4 u; u.x = f2bf(e1.x); u.y = f2bf(e1.y); u.z = f2bf(e1.z); u.w = f2bf(e1.w);
            *(ushort4*)(rowp + (16 + s) * EDIM + d * 4) = u;
        }

        float a0x=0,a0y=0,a0z=0,a0w=0, a1x=0,a1y=0,a1z=0,a1w=0, m0=0, m1=0;
        #pragma unroll
        for (int p = 0; p < 7; ++p) {
            int pi = p * 16 + s;
            float m = mmk[p];
            if (pi >= 50) { a1x += m*gm[p].x; a1y += m*gm[p].y; a1z += m*gm[p].z; a1w += m*gm[p].w; m1 += m; }
            else          { a0x += m*gm[p].x; a0y += m*gm[p].y; a0z += m*gm[p].z; a0w += m*gm[p].w; m0 += m; }
        }

        float ohx = e0.x + e1.x, ohy = e0.y + e1.y, ohz = e0.z + e1.z, ohw = e0.w + e1.w;
        float qx = e0.x*e0.x + e1.x*e1.x, qy = e0.y*e0.y + e1.y*e1.y;
        float qz = e0.z*e0.z + e1.z*e1.z, qw = e0.w*e0.w + e1.w*e1.w;

#define R4(v) { v += __shfl_xor(v, 4); v += __shfl_xor(v, 8); v += __shfl_xor(v, 16); v += __shfl_xor(v, 32); }
        R4(a0x) R4(a0y) R4(a0z) R4(a0w)
        R4(a1x) R4(a1y) R4(a1z) R4(a1w)
        R4(m0)  R4(m1)
        R4(ohx) R4(ohy) R4(ohz) R4(ohw)
        R4(qx)  R4(qy)  R4(qz)  R4(qw)
        R4(wsum)
#undef R4

        float inv0 = 1.f / fmaxf(m0, 1.f);
        float inv1 = 1.f / fmaxf(m1, 1.f);
        float h0x = a0x*inv0, h0y = a0y*inv0, h0z = a0z*inv0, h0w = a0w*inv0;
        float h1x = a1x*inv1, h1y = a1y*inv1, h1z = a1z*inv1, h1w = a1w*inv1;

        if (s == 0) {
            ushort4 u; u.x = f2bf(h0x); u.y = f2bf(h0y); u.z = f2bf(h0z); u.w = f2bf(h0w);
            *(ushort4*)(rowp + 26 * EDIM + d * 4) = u;
        }
        if (s == 1) {
            ushort4 u; u.x = f2bf(h1x); u.y = f2bf(h1y); u.z = f2bf(h1z); u.w = f2bf(h1w);
            *(ushort4*)(rowp + 27 * EDIM + d * 4) = u;
        }

        float sx = ohx + h0x + h1x, sy = ohy + h0y + h1y, sz = ohz + h0z + h1z, sw = ohw + h0w + h1w;
        float tx = qx + h0x*h0x + h1x*h1x, ty = qy + h0y*h0y + h1y*h1y;
        float tz = qz + h0z*h0z + h1z*h1z, tw = qw + h0w*h0w + h1w*h1w;
        float f2x = 0.5f * (sx*sx - tx), f2y = 0.5f * (sy*sy - ty);
        float f2z = 0.5f * (sz*sz - tz), f2w = 0.5f * (sw*sw - tw);

        float cw0 = concat_w[0];
        float c0 = concat_w[1 + d*4 + 0], c1 = concat_w[1 + d*4 + 1];
        float c2 = concat_w[1 + d*4 + 2], c3 = concat_w[1 + d*4 + 3];
        float part = f2x*c0 + f2y*c1 + f2z*c2 + f2w*c3 + wsum * cw0;
        part += __shfl_xor(part, 1);
        part += __shfl_xor(part, 2);
        if (l == 0) part_s[r] = part + concat_b[0];

        if (l < 32) {
            float v = (l < 13) ? dense[b * 13 + l] : 0.f;
            rowp[448 + l] = f2bf(v);
        }
    };

    const int c = l & 15, g = l >> 4;

    auto gemm_half = [&](int h, int nt) {
        f32x4 acc = {0.f, 0.f, 0.f, 0.f};
        const unsigned short* ap = As + (h * 16 + c) * KLDS + (g << 3);
        const unsigned short* bgp = w0f + ((size_t)(nt * 15) * 64 + l) * 8;
        #pragma unroll
        for (int kt = 0; kt < 15; ++kt) {
            bf16x8 a = *(const bf16x8*)(ap + kt * 32);
            bf16x8 bb = *(const bf16x8*)(bgp + (size_t)kt * 64 * 8);
            acc = __builtin_amdgcn_mfma_f32_16x16x32_bf16(a, bb, acc, 0, 0, 0);
        }
        // C layout: col = lane&15, row = (lane>>4)*4 + reg
        #pragma unroll
        for (int reg = 0; reg < 4; ++reg)
            h0s[h * 16 + g * 4 + reg][nt * 16 + c] = f2bf(fmaxf(acc[reg] + b0s[nt * 16 + c], 0.f));
    };

    auto tail_half = [&](int h) {
        float s0 = b1s[g*3 + 0], s1 = b1s[g*3 + 1], s2 = b1s[g*3 + 2];
        const unsigned short* hrow = &h0s[h * 16 + c][0];
        #pragma unroll
        for (int k8 = 0; k8 < 8; ++k8) {
            ushort4 ha = *(const ushort4*)(hrow + k8 * 8 + 0);
            ushort4 hb = *(const ushort4*)(hrow + k8 * 8 + 4);
            float hv[8] = { bf2f(ha.x), bf2f(ha.y), bf2f(ha.z), bf2f(ha.w),
                            bf2f(hb.x), bf2f(hb.y), bf2f(hb.z), bf2f(hb.w) };
            #pragma unroll
            for (int j = 0; j < 8; ++j) {
                int k = k8 * 8 + j;
                s0 += hv[j] * w1t[(g*3 + 0) * 64 + k];
                s1 += hv[j] * w1t[(g*3 + 1) * 64 + k];
                s2 += hv[j] * w1t[(g*3 + 2) * 64 + k];
            }
        }
        float hd = fmaxf(s0, 0.f)*cwh[g*3] + fmaxf(s1, 0.f)*cwh[g*3+1] + fmaxf(s2, 0.f)*cwh[g*3+2];
        hd += __shfl_xor(hd, 16);
        hd += __shfl_xor(hd, 32);
        if (g == 0) {
            int rr = row0 + h * 16 + c;
            float x = part_s[h * 16 + c] + hd;
            out[rr] = 1.f / (1.f + __expf(-x));
        }
    };

    // ---- S1: all waves gather rows 0..15 (2 each) ----
    gather_row(wv * 2 + 0);
    gather_row(wv * 2 + 1);
    __syncthreads();

    // ---- S2: waves 0-3 GEMM half0 || waves 4-7 gather rows 16..31 (4 each) ----
    if (wv < 4) {
        gemm_half(0, wv);
    } else {
        const int base = 16 + (wv - 4) * 4;
        gather_row(base + 0);
        gather_row(base + 1);
        gather_row(base + 2);
        gather_row(base + 3);
    }
    __syncthreads();

    // ---- S3: waves 0-3 GEMM half1 || wave 4 tail half0 ----
    if (wv < 4) {
        gemm_half(1, wv);
    } else if (wv == 4) {
        tail_half(0);
    }
    __syncthreads();

    // ---- S4: wave 0 tail half1 ----
    if (wv == 0) tail_half(1);
}

extern "C" void kernel_launch(void* const* d_in, const int* in_sizes, int n_in,
                              void* d_out, int out_size, void* d_ws, size_t ws_size,
                              hipStream_t stream) {
    const float* dense   = (const float*)d_in[0];
    const int*   onehot  = (const int*)  d_in[1];
    const int*   mh_ids  = (const int*)  d_in[2];
    const float* mh_mask = (const float*)d_in[3];
    const float* fm_w    = (const float*)d_in[4];
    const float* fm_emb  = (const float*)d_in[5];
    const float* w0      = (const float*)d_in[6];
    const float* b0      = (const float*)d_in[7];
    const float* w1      = (const float*)d_in[8];
    const float* b1      = (const float*)d_in[9];
    const float* cw      = (const float*)d_in[10];
    const float* cb      = (const float*)d_in[11];

    unsigned short* w0f = (unsigned short*)d_ws;   // 61,440 B

    hipLaunchKernelGGL(prep, dim3(120), dim3(256), 0, stream, w0, w0f);
    hipLaunchKernelGGL(fused, dim3(BATCH / ROWS), dim3(512), 0, stream,
                       dense, onehot, mh_ids, mh_mask, fm_w, fm_emb,
                       w0f, b0, w1, b1, cw, cb, (float*)d_out);
}